// Round 3
// baseline (850.875 us; speedup 1.0000x reference)
//
#include <hip/hip_runtime.h>
#include <hip/hip_bf16.h>

#define BB 8
#define CC 16
#define HH 128
#define WW 128
#define HD 64
#define WD 64
#define LP 4096
#define K1 144
#define KP 160
#define N2 256

typedef __attribute__((ext_vector_type(8))) short bf16x8;
typedef __attribute__((ext_vector_type(4))) float f32x4;

__device__ __forceinline__ unsigned short pack_rne(float x) {
    unsigned int u = __float_as_uint(x);
    return (unsigned short)((u + 0x7FFFu + ((u >> 16) & 1u)) >> 16);
}
__device__ __forceinline__ float bf2f(unsigned short u) {
    return __uint_as_float(((unsigned int)u) << 16);
}
__device__ __forceinline__ float ld_in(const void* p, long idx, int bf) {
    if (bf) return bf2f(((const unsigned short*)p)[idx]);
    return ((const float*)p)[idx];
}

// ---------------------------------------------------------------------------
__global__ void detect_kernel(const unsigned int* __restrict__ w, int* __restrict__ flag) {
    if (threadIdx.x == 0) {
        int cnt = 0;
        for (int i = 0; i < 256; i++) {
            unsigned int e = (w[i] >> 7) & 0xFF;
            if (e >= 100 && e <= 140) cnt++;
        }
        *flag = (cnt >= 192) ? 1 : 0;
    }
}

// ---------------------------------------------------------------------------
// prep v2: ONE WAVE per patch (round-2 counters: tid0's serial 144-element
// reduction was ~75% of the kernel). Shuffle-butterfly reductions, no LDS,
// no barriers. 4 patches/block, grid 8192.
// ---------------------------------------------------------------------------
__global__ __launch_bounds__(256) void prep_kernel(
    const void* __restrict__ fg, const void* __restrict__ bg,
    const void* __restrict__ mask, const int* __restrict__ flagp,
    unsigned short* __restrict__ Fh, unsigned short* __restrict__ Fl,
    unsigned short* __restrict__ Kh, unsigned short* __restrict__ Kl,
    float* __restrict__ mmg)
{
    int bf = *flagp;
    int wave = threadIdx.x >> 6, lane = threadIdx.x & 63;
    int bl = blockIdx.x * 4 + wave;
    int b = bl >> 12, l = bl & 4095;
    int py = l >> 6, px = l & 63;

    float fgv[3], bgv[3];
    float ss = 0.f;
#pragma unroll
    for (int j = 0; j < 3; j++) {
        int e = lane + 64 * j;
        fgv[j] = 0.f; bgv[j] = 0.f;
        if (e < K1) {
            int c = e / 9;
            int r9 = e - c * 9;
            int ky = r9 / 3, kx = r9 - ky * 3;
            int yy = py + ky - 1, xx = px + kx - 1;
            if (yy >= 0 && yy < HD && xx >= 0 && xx < WD) {
                long base = ((long)(b * CC + c) * HH + 2 * yy) * WW + 2 * xx;
                fgv[j] = ld_in(fg, base, bf);
                bgv[j] = ld_in(bg, base, bf);
            }
        }
        ss += bgv[j] * bgv[j];
    }
#pragma unroll
    for (int s = 1; s < 64; s <<= 1) ss += __shfl_xor(ss, s);
    float rn = 1.0f / fmaxf(sqrtf(ss), 1e-4f);

    // mask sum over the 9 patch positions (channel-independent)
    float mv = 0.f;
    if (lane < 9) {
        int ky = lane / 3, kx = lane - ky * 3;
        int yy = py + ky - 1, xx = px + kx - 1;
        if (yy >= 0 && yy < HD && xx >= 0 && xx < WD)
            mv = ld_in(mask, ((long)b * HH + 2 * yy) * WW + 2 * xx, bf);
    }
#pragma unroll
    for (int s = 1; s < 16; s <<= 1) mv += __shfl_xor(mv, s);
    if (lane == 0) mmg[bl] = (mv == 0.0f) ? 1.0f : 0.0f;

    long base = (long)bl * KP;
#pragma unroll
    for (int j = 0; j < 3; j++) {
        int e = lane + 64 * j;
        if (e < KP) {
            float f = fgv[j];               // 0 beyond K1 -> zero pad
            float kv = bgv[j] * rn;         // 0 beyond K1
            unsigned short fh = pack_rne(f);
            unsigned short fl = pack_rne(f - bf2f(fh));
            unsigned short kh = pack_rne(kv);
            unsigned short kl = pack_rne(kv - bf2f(kh));
            Fh[base + e] = fh; Fl[base + e] = fl;
            Kh[base + e] = kh; Kl[base + e] = kl;
        }
    }
}

// ---------------------------------------------------------------------------
__global__ __launch_bounds__(256) void vT_kernel(
    const void* __restrict__ bg, const int* __restrict__ flagp,
    unsigned short* __restrict__ VT)
{
    int bf = *flagp;
    int l0 = blockIdx.x * 16;
    int b = blockIdx.y;
    int j = threadIdx.x;
    int c = j >> 4, dy = (j >> 2) & 3, dx = j & 3;

    unsigned short buf[16];
#pragma unroll
    for (int i = 0; i < 16; i++) {
        int l = l0 + i;
        int ly = l >> 6, lx = l & 63;
        int Y = 2 * ly + dy - 1, X = 2 * lx + dx - 1;
        float v = 0.f;
        if (Y >= 0 && Y < HH && X >= 0 && X < WW)
            v = ld_in(bg, ((long)(b * CC + c) * HH + Y) * WW + X, bf);
        buf[i] = pack_rne(v);
    }
    uint4* dst = (uint4*)&VT[((size_t)(b * N2 + j)) * LP + l0];
    dst[0] = *(uint4*)&buf[0];
    dst[1] = *(uint4*)&buf[8];
}

// ---------------------------------------------------------------------------
// gemmZ v2: split-bf16 MFMA, 128x64 tile, BK=32; double-buffered LDS, one
// barrier per K-step, reg-staged prefetch (validated on gemmU in round 1/2).
// LDS 2*(AhS+AlS+BhS+BlS) = 61.4 KB.
// ---------------------------------------------------------------------------
__global__ __launch_bounds__(256) void gemmZ_mfma_kernel(
    const unsigned short* __restrict__ Ah, const unsigned short* __restrict__ Al,
    const unsigned short* __restrict__ Bh, const unsigned short* __restrict__ Bl,
    const float* __restrict__ mmv, float* __restrict__ Z)
{
    __shared__ unsigned short AhS[2][128][40];
    __shared__ unsigned short AlS[2][128][40];
    __shared__ unsigned short BhS[2][64][40];
    __shared__ unsigned short BlS[2][64][40];

    int t = threadIdx.x;
    int l0 = blockIdx.x * 64, p0 = blockIdx.y * 128;
    int wave = t >> 6, lane = t & 63;
    int lrow = lane & 15, lq = lane >> 4;

    f32x4 zero4 = {0.f, 0.f, 0.f, 0.f};
    f32x4 acc[2][4];
#pragma unroll
    for (int i = 0; i < 2; i++)
#pragma unroll
        for (int n = 0; n < 4; n++) acc[i][n] = zero4;

    int arow = t >> 1, ahalf = (t & 1) * 16;
    int brow = t >> 2, bq = (t & 3) * 8;

    const size_t abase = (size_t)(p0 + arow) * KP + ahalf;
    const size_t bbase = (size_t)(l0 + brow) * KP + bq;

    uint4 ah0 = *(const uint4*)&Ah[abase];
    uint4 ah1 = *(const uint4*)&Ah[abase + 8];
    uint4 al0 = *(const uint4*)&Al[abase];
    uint4 al1 = *(const uint4*)&Al[abase + 8];
    uint4 bh0 = *(const uint4*)&Bh[bbase];
    uint4 bl0 = *(const uint4*)&Bl[bbase];
    *(uint4*)&AhS[0][arow][ahalf] = ah0;
    *(uint4*)&AhS[0][arow][ahalf + 8] = ah1;
    *(uint4*)&AlS[0][arow][ahalf] = al0;
    *(uint4*)&AlS[0][arow][ahalf + 8] = al1;
    *(uint4*)&BhS[0][brow][bq] = bh0;
    *(uint4*)&BlS[0][brow][bq] = bl0;
    __syncthreads();

    for (int it = 0; it < 5; ++it) {
        int cur = it & 1;
        if (it < 4) {
            size_t off = (size_t)(it + 1) * 32;
            ah0 = *(const uint4*)&Ah[abase + off];
            ah1 = *(const uint4*)&Ah[abase + off + 8];
            al0 = *(const uint4*)&Al[abase + off];
            al1 = *(const uint4*)&Al[abase + off + 8];
            bh0 = *(const uint4*)&Bh[bbase + off];
            bl0 = *(const uint4*)&Bl[bbase + off];
        }

        bf16x8 ahf[2], alf[2], bhf[4], blf[4];
#pragma unroll
        for (int i = 0; i < 2; i++) {
            ahf[i] = *(const bf16x8*)&AhS[cur][wave * 32 + i * 16 + lrow][lq * 8];
            alf[i] = *(const bf16x8*)&AlS[cur][wave * 32 + i * 16 + lrow][lq * 8];
        }
#pragma unroll
        for (int n = 0; n < 4; n++) {
            bhf[n] = *(const bf16x8*)&BhS[cur][n * 16 + lrow][lq * 8];
            blf[n] = *(const bf16x8*)&BlS[cur][n * 16 + lrow][lq * 8];
        }
#pragma unroll
        for (int i = 0; i < 2; i++)
#pragma unroll
            for (int n = 0; n < 4; n++) {
                acc[i][n] = __builtin_amdgcn_mfma_f32_16x16x32_bf16(ahf[i], bhf[n], acc[i][n], 0, 0, 0);
                acc[i][n] = __builtin_amdgcn_mfma_f32_16x16x32_bf16(ahf[i], blf[n], acc[i][n], 0, 0, 0);
                acc[i][n] = __builtin_amdgcn_mfma_f32_16x16x32_bf16(alf[i], bhf[n], acc[i][n], 0, 0, 0);
            }

        if (it < 4) {
            int nxt = cur ^ 1;
            *(uint4*)&AhS[nxt][arow][ahalf] = ah0;
            *(uint4*)&AhS[nxt][arow][ahalf + 8] = ah1;
            *(uint4*)&AlS[nxt][arow][ahalf] = al0;
            *(uint4*)&AlS[nxt][arow][ahalf + 8] = al1;
            *(uint4*)&BhS[nxt][brow][bq] = bh0;
            *(uint4*)&BlS[nxt][brow][bq] = bl0;
        }
        __syncthreads();
    }

#pragma unroll
    for (int i = 0; i < 2; i++)
#pragma unroll
        for (int n = 0; n < 4; n++) {
            int row = p0 + wave * 32 + i * 16 + lq * 4;
            int col = l0 + n * 16 + lrow;
            float mmc = mmv[col];
#pragma unroll
            for (int r = 0; r < 4; r++) {
                float z = (mmc > 0.f) ? 10.0f * acc[i][n][r] : 0.f;
                Z[(size_t)(row + r) * LP + col] = z;
            }
        }
}

// ---------------------------------------------------------------------------
// statsW v3: softmax per row; wave shuffle-butterfly reductions + 4-entry
// cross-wave LDS combine (2 barriers instead of 16).
// ---------------------------------------------------------------------------
__global__ __launch_bounds__(256) void statsW_kernel(
    float* __restrict__ Z, const float* __restrict__ mmv)
{
    int p = blockIdx.x;
    int t = threadIdx.x;
    int wave = t >> 6, lane = t & 63;
    float4* Z4 = (float4*)(Z + (size_t)p * LP);
    __shared__ float wred[4];
    __shared__ float wred2[4];

    float4 z[4];
    float mx = -1e30f;
#pragma unroll
    for (int i = 0; i < 4; i++) {
        z[i] = Z4[t + 256 * i];
        mx = fmaxf(mx, fmaxf(fmaxf(z[i].x, z[i].y), fmaxf(z[i].z, z[i].w)));
    }
#pragma unroll
    for (int s = 1; s < 64; s <<= 1) mx = fmaxf(mx, __shfl_xor(mx, s));
    if (lane == 0) wred[wave] = mx;
    __syncthreads();
    float m = fmaxf(fmaxf(wred[0], wred[1]), fmaxf(wred[2], wred[3]));

    float4 e[4];
    float sum = 0.f;
#pragma unroll
    for (int i = 0; i < 4; i++) {
        e[i].x = expf(z[i].x - m);
        e[i].y = expf(z[i].y - m);
        e[i].z = expf(z[i].z - m);
        e[i].w = expf(z[i].w - m);
        sum += e[i].x + e[i].y + e[i].z + e[i].w;
    }
#pragma unroll
    for (int s = 1; s < 64; s <<= 1) sum += __shfl_xor(sum, s);
    if (lane == 0) wred2[wave] = sum;
    __syncthreads();
    float dinv = 1.0f / (wred2[0] + wred2[1] + wred2[2] + wred2[3]);

    const float4* mm4 = (const float4*)mmv;
    uint2* W2 = (uint2*)(Z + (size_t)p * LP);
#pragma unroll
    for (int i = 0; i < 4; i++) {
        float4 mm = mm4[t + 256 * i];
        uint2 pk;
        pk.x = (unsigned)pack_rne(e[i].x * dinv * mm.x) |
               ((unsigned)pack_rne(e[i].y * dinv * mm.y) << 16);
        pk.y = (unsigned)pack_rne(e[i].z * dinv * mm.z) |
               ((unsigned)pack_rne(e[i].w * dinv * mm.w) << 16);
        W2[t + 256 * i] = pk;
    }
}

// ---------------------------------------------------------------------------
// gemmU via bf16 MFMA, tile 64p x 256c, split-K=8, plain stores to U8 slabs
// (disjoint tiles, no atomics), double-buffered LDS, one barrier per K-step.
// Grid (64 p-tiles, 8 kz). LDS: 2*(Ws 64x40 + Vs 256x40) = 51.2 KB.
// ---------------------------------------------------------------------------
__global__ __launch_bounds__(256) void gemmU_mfma_kernel(
    const unsigned short* __restrict__ W16,   // [4096][stride 8192]
    const unsigned short* __restrict__ VT,    // [256][4096]
    float* __restrict__ U8)                   // [8][4096][256]
{
    __shared__ unsigned short Ws[2][64][40];
    __shared__ unsigned short Vs[2][256][40];

    int t = threadIdx.x;
    int p0 = blockIdx.x * 64;
    int kz = blockIdx.y;

    int wave = t >> 6, lane = t & 63;
    int lrow = lane & 15, lq = lane >> 4;

    f32x4 zero4 = {0.f, 0.f, 0.f, 0.f};
    f32x4 acc[4][4];
#pragma unroll
    for (int i = 0; i < 4; i++)
#pragma unroll
        for (int n = 0; n < 4; n++) acc[i][n] = zero4;

    int wrow = t >> 2, wq = (t & 3) * 8;   // loader: 64 rows x 4 k-octets

    const size_t wbase = (size_t)(p0 + wrow) * 8192 + (size_t)kz * 512 + wq;
    const size_t vbase = (size_t)wrow * LP + (size_t)kz * 512 + wq;

    // prologue: stage iter 0 into buf 0
    uint4 w0 = *(const uint4*)&W16[wbase];
    uint4 v0 = *(const uint4*)&VT[vbase];
    uint4 v1 = *(const uint4*)&VT[vbase + (size_t)64 * LP];
    uint4 v2 = *(const uint4*)&VT[vbase + (size_t)128 * LP];
    uint4 v3 = *(const uint4*)&VT[vbase + (size_t)192 * LP];
    *(uint4*)&Ws[0][wrow][wq] = w0;
    *(uint4*)&Vs[0][wrow][wq] = v0;
    *(uint4*)&Vs[0][wrow + 64][wq] = v1;
    *(uint4*)&Vs[0][wrow + 128][wq] = v2;
    *(uint4*)&Vs[0][wrow + 192][wq] = v3;
    __syncthreads();

    for (int it = 0; it < 16; ++it) {
        int cur = it & 1;
        if (it < 15) {
            size_t off = (size_t)(it + 1) * 32;
            w0 = *(const uint4*)&W16[wbase + off];
            v0 = *(const uint4*)&VT[vbase + off];
            v1 = *(const uint4*)&VT[vbase + (size_t)64 * LP + off];
            v2 = *(const uint4*)&VT[vbase + (size_t)128 * LP + off];
            v3 = *(const uint4*)&VT[vbase + (size_t)192 * LP + off];
        }

        bf16x8 a[4], b[4];
#pragma unroll
        for (int i = 0; i < 4; i++)
            a[i] = *(const bf16x8*)&Ws[cur][i * 16 + lrow][lq * 8];
#pragma unroll
        for (int n = 0; n < 4; n++)
            b[n] = *(const bf16x8*)&Vs[cur][wave * 64 + n * 16 + lrow][lq * 8];
#pragma unroll
        for (int i = 0; i < 4; i++)
#pragma unroll
            for (int n = 0; n < 4; n++)
                acc[i][n] = __builtin_amdgcn_mfma_f32_16x16x32_bf16(a[i], b[n], acc[i][n], 0, 0, 0);

        if (it < 15) {
            int nxt = cur ^ 1;
            *(uint4*)&Ws[nxt][wrow][wq] = w0;
            *(uint4*)&Vs[nxt][wrow][wq] = v0;
            *(uint4*)&Vs[nxt][wrow + 64][wq] = v1;
            *(uint4*)&Vs[nxt][wrow + 128][wq] = v2;
            *(uint4*)&Vs[nxt][wrow + 192][wq] = v3;
        }
        __syncthreads();
    }

    float* Uo = U8 + (size_t)kz * LP * N2;
#pragma unroll
    for (int i = 0; i < 4; i++)
#pragma unroll
        for (int n = 0; n < 4; n++) {
            int row = p0 + i * 16 + lq * 4;
            int col = wave * 64 + n * 16 + lrow;
#pragma unroll
            for (int r = 0; r < 4; r++)
                Uo[(size_t)(row + r) * N2 + col] = acc[i][n][r];
        }
}

// ---------------------------------------------------------------------------
// reduceU: U[b] = sum_kz U8[kz]; pure HBM streaming (32 MB read, 4 MB write).
// ---------------------------------------------------------------------------
__global__ __launch_bounds__(256) void reduceU_kernel(
    const float4* __restrict__ U8, float4* __restrict__ U)
{
    int i = blockIdx.x * 256 + threadIdx.x;
    float4 s = U8[i];
#pragma unroll
    for (int k = 1; k < 8; k++) {
        float4 v = U8[(size_t)k * (LP * N2 / 4) + i];
        s.x += v.x; s.y += v.y; s.z += v.z; s.w += v.w;
    }
    U[i] = s;
}

// ---------------------------------------------------------------------------
// gather / overlap-add (upright), fp32 out
// ---------------------------------------------------------------------------
__global__ __launch_bounds__(256) void gather_kernel(
    const float* __restrict__ U, float* __restrict__ out)
{
    int idx = blockIdx.x * 256 + threadIdx.x;
    int ox = idx & 127;
    int t1 = idx >> 7;
    int oy = t1 & 127;
    int t2 = t1 >> 7;
    int c = t2 & 15;
    int b = t2 >> 4;

    float sum = 0.f;
    int d0y = (oy + 1) & 1, d0x = (ox + 1) & 1;
#pragma unroll
    for (int iy = 0; iy < 2; iy++) {
        int dy = d0y + 2 * iy;
        int y = (oy + 1 - dy) >> 1;
        if (y < 0 || y > 63) continue;
#pragma unroll
        for (int ix = 0; ix < 2; ix++) {
            int dx = d0x + 2 * ix;
            int x = (ox + 1 - dx) >> 1;
            if (x < 0 || x > 63) continue;
            sum += U[((long)b * LP + y * 64 + x) * N2 + c * 16 + dy * 4 + dx];
        }
    }
    out[idx] = sum * 0.25f;
}

// ---------------------------------------------------------------------------
extern "C" void kernel_launch(void* const* d_in, const int* in_sizes, int n_in,
                              void* d_out, int out_size, void* d_ws, size_t ws_size,
                              hipStream_t stream)
{
    const void* fg   = d_in[0];
    const void* bg   = d_in[1];
    const void* mask = d_in[2];
    float* out = (float*)d_out;

    char* w = (char*)d_ws;
    size_t o = 0;
    int*            flag = (int*)(w + o);            o += 16;
    unsigned short* Fh   = (unsigned short*)(w + o); o += (size_t)BB * LP * KP * 2;
    unsigned short* Fl   = (unsigned short*)(w + o); o += (size_t)BB * LP * KP * 2;
    unsigned short* Kh   = (unsigned short*)(w + o); o += (size_t)BB * LP * KP * 2;
    unsigned short* Kl   = (unsigned short*)(w + o); o += (size_t)BB * LP * KP * 2;
    unsigned short* VT   = (unsigned short*)(w + o); o += (size_t)BB * N2 * LP * 2;
    float*          U    = (float*)(w + o);          o += (size_t)BB * LP * N2 * 4;
    float*          mmg  = (float*)(w + o);          o += (size_t)BB * LP * 4;
    float*          Z    = (float*)(w + o);          o += (size_t)LP * LP * 4;
    float*          U8   = (float*)(w + o);          o += (size_t)8 * LP * N2 * 4;

    detect_kernel<<<1, 64, 0, stream>>>((const unsigned int*)fg, flag);
    prep_kernel<<<BB * LP / 4, 256, 0, stream>>>(fg, bg, mask, flag, Fh, Fl, Kh, Kl, mmg);
    vT_kernel<<<dim3(LP / 16, BB), 256, 0, stream>>>(bg, flag, VT);

    for (int b = 0; b < BB; b++) {
        gemmZ_mfma_kernel<<<dim3(64, 32), 256, 0, stream>>>(
            Fh + (size_t)b * LP * KP, Fl + (size_t)b * LP * KP,
            Kh + (size_t)b * LP * KP, Kl + (size_t)b * LP * KP,
            mmg + (size_t)b * LP, Z);
        statsW_kernel<<<LP, 256, 0, stream>>>(Z, mmg + (size_t)b * LP);
        gemmU_mfma_kernel<<<dim3(64, 8), 256, 0, stream>>>(
            (const unsigned short*)Z, VT + (size_t)b * N2 * LP, U8);
        reduceU_kernel<<<LP * N2 / 4 / 256, 256, 0, stream>>>(
            (const float4*)U8, (float4*)(U + (size_t)b * LP * N2));
    }

    gather_kernel<<<(BB * CC * HH * WW) / 256, 256, 0, stream>>>(U, out);
}